// Round 10
// baseline (112.476 us; speedup 1.0000x reference)
//
#include <hip/hip_runtime.h>
#include <hip/hip_bf16.h>

// CustomAttention: proj = tanh(H @ W^T + b); scores = proj @ c; attn = softmax_L(scores);
// out0 = sum_l H * attn ; out1 = attn.   B=64, L=512, D=768.  M = B*L = 32768.
// Round 10: clean occupancy test. r4's proven structure (128x128, dbuf, single
// barrier/step, XCD affinity) at BK=32 so LDS = 33.8 KB -> 4 blocks/CU resident
// (was 2).  Bank-conflict-free at BK=32 via the r8/r9-measured packed-pair
// 128-B-row layout (r5's failure used a broken 64-B-row swizzle + spill squeeze).

using half8 = __attribute__((ext_vector_type(8))) _Float16;   // MFMA A/B frag (4 VGPRs)
using f32x4 = __attribute__((ext_vector_type(4))) float;      // MFMA C/D frag

#define AS1 __attribute__((address_space(1)))
#define AS3 __attribute__((address_space(3)))

__device__ __forceinline__ void gload_lds16(const void* g, void* l) {
  __builtin_amdgcn_global_load_lds((const AS1 void*)g, (AS3 void*)l, 16, 0, 0);
}

__device__ __forceinline__ unsigned short f2h(float x) {
  _Float16 h = (_Float16)x;                       // v_cvt_f16_f32, RNE
  return __builtin_bit_cast(unsigned short, h);
}

// tanh(x) = 1 - 2/(exp(2x)+1).
__device__ __forceinline__ float tanh_fast(float x) {
  return 1.0f - __fdividef(2.0f, 1.0f + __expf(2.0f * x));
}

// ---------------- conversion kernels ----------------

__global__ void convert_h(const float4* __restrict__ H4, ushort4* __restrict__ Ah) {
  int i = blockIdx.x * 256 + threadIdx.x;   // 6291456 quads
  float4 x = H4[i];
  ushort4 o;
  o.x = f2h(x.x); o.y = f2h(x.y); o.z = f2h(x.z); o.w = f2h(x.w);
  Ah[i] = o;
}

__global__ void convert_w(const float4* __restrict__ W4, ushort4* __restrict__ Wt) {
  int i = blockIdx.x * 256 + threadIdx.x;   // 147456 quads
  float4 x = W4[i];
  ushort4 o;
  o.x = f2h(x.x); o.y = f2h(x.y); o.z = f2h(x.z); o.w = f2h(x.w);
  Wt[i] = o;
}

// ---------------- GEMM (128x128, BK=32, 4 blocks/CU) + tanh/context epilogue ----
// LDS packed-pair 128-B rows (r8/r9 measured 0 conflicts):
//   tile rows [0,128) x k [0,32) -> 64 ldsrows x 128 B:
//   half=row>>6, lr=row&63, u'=half*4+(k>>3), slot=u'^(lr&7),
//   byte = lr*128 + slot*16 + (k&7)*2.
// Staging writes LDS linearly (gload_lds: wave-uniform base + lane*16); global
// SOURCE address is the layout inverse (both-sides rule).
// Grid: flat 1536; XCD decode (bid&7) keeps the 6 same-mtile blocks on one XCD.
__global__ __launch_bounds__(256) void gemm_scores(
    const ushort* __restrict__ Ah, const ushort* __restrict__ Wt,
    const float* __restrict__ bias, const float* __restrict__ cvec,
    float* __restrict__ part) {
  __shared__ ushort ldsA[2][4096];    // 2 x 8 KB
  __shared__ ushort ldsB[2][4096];    // 2 x 8 KB
  __shared__ float scpart[2][128];    // 1 KB  (total 33792 B -> 4 blocks/CU)

  const int tid = threadIdx.x;
  const int lane = tid & 63;
  const int wid = tid >> 6;           // 0..3
  const int wr = wid >> 1, wc = wid & 1;
  const int m = lane & 15, q = lane >> 4;

  const int bid = blockIdx.x;         // 0..1535
  const int xcd = bid & 7;
  const int slot = bid >> 3;          // 0..191
  const int mtile = xcd * 32 + slot / 6;
  const int ntile = slot % 6;

  const char* const Abase = (const char*)Ah + (size_t)(mtile * 128) * 1536;
  const char* const Bbase = (const char*)Wt + (size_t)(ntile * 128) * 1536;

  // staging source inverse: thread t, chunk c writes LDS byte c*4096 + t*16
  //   lr = c*32 + (t>>3), slot = t&7, u' = slot ^ (lr&7)  (c*32 % 8 == 0)
  //   row = (u'>>2)*64 + lr, col16 = u'&3
  const int up = (tid & 7) ^ ((tid >> 3) & 7);
  const int lr_s = tid >> 3;          // 0..31
  const size_t src0 = (size_t)((up >> 2) * 64 + lr_s) * 1536 + (up & 3) * 16;
  const size_t src1 = (size_t)((up >> 2) * 64 + 32 + lr_s) * 1536 + (up & 3) * 16;
  const int wavebase = wid << 10;

  f32x4 acc[4][4];
  #pragma unroll
  for (int i = 0; i < 4; ++i)
    #pragma unroll
    for (int j = 0; j < 4; ++j)
      acc[i][j] = (f32x4){0.f, 0.f, 0.f, 0.f};

  auto stage = [&](int kt, int s) {
    gload_lds16(Abase + src0 + kt * 64, (char*)ldsA[s] + wavebase);
    gload_lds16(Abase + src1 + kt * 64, (char*)ldsA[s] + 4096 + wavebase);
    gload_lds16(Bbase + src0 + kt * 64, (char*)ldsB[s] + wavebase);
    gload_lds16(Bbase + src1 + kt * 64, (char*)ldsB[s] + 4096 + wavebase);
  };

  // read-side: logical row wr*64 + mi*16 + m -> half=wr, lr=mi*16+m,
  // u' = wr*4 + q, byte = lr*128 + ((wr*4+q)^(m&7))*16
  const int aslot = ((wr * 4 + q) ^ (m & 7)) * 16;
  const int bslot = ((wc * 4 + q) ^ (m & 7)) * 16;

  auto compute = [&](int s) {
    const char* Ab = (const char*)ldsA[s];
    const char* Bb = (const char*)ldsB[s];
    half8 areg[4], breg[4];
    #pragma unroll
    for (int mi = 0; mi < 4; ++mi)
      areg[mi] = *(const half8*)(Ab + (mi * 16 + m) * 128 + aslot);
    #pragma unroll
    for (int ni = 0; ni < 4; ++ni)
      breg[ni] = *(const half8*)(Bb + (ni * 16 + m) * 128 + bslot);
    #pragma unroll
    for (int mi = 0; mi < 4; ++mi)
      #pragma unroll
      for (int ni = 0; ni < 4; ++ni)
        acc[mi][ni] = __builtin_amdgcn_mfma_f32_16x16x32_f16(
            areg[mi], breg[ni], acc[mi][ni], 0, 0, 0);
  };

  // --- dbuf loop: stage(t+1) | compute(t) | sync  (r4-proven) ---
  stage(0, 0);
  __syncthreads();
  #pragma unroll
  for (int kb2 = 0; kb2 < 12; ++kb2) {
    stage(2 * kb2 + 1, 1);
    compute(0);
    __syncthreads();
    if (kb2 < 11) stage(2 * kb2 + 2, 0);
    compute(1);
    __syncthreads();
  }

  // epilogue: score partial = sum_e tanh(acc + b[e]) * c[e]
  float bb[4], cc[4];
  #pragma unroll
  for (int ni = 0; ni < 4; ++ni) {
    int e = ntile * 128 + wc * 64 + ni * 16 + m;
    bb[ni] = bias[e];
    cc[ni] = cvec[e];
  }
  #pragma unroll
  for (int mi = 0; mi < 4; ++mi) {
    #pragma unroll
    for (int j = 0; j < 4; ++j) {
      float s = 0.f;
      #pragma unroll
      for (int ni = 0; ni < 4; ++ni)
        s += tanh_fast(acc[mi][ni][j] + bb[ni]) * cc[ni];
      s += __shfl_xor(s, 1);
      s += __shfl_xor(s, 2);
      s += __shfl_xor(s, 4);
      s += __shfl_xor(s, 8);
      if (m == 0) scpart[wc][wr * 64 + mi * 16 + q * 4 + j] = s;
    }
  }
  __syncthreads();
  if (tid < 128)
    part[ntile * 32768 + mtile * 128 + tid] = scpart[0][tid] + scpart[1][tid];
}

// ---------------- fused softmax + weighted sum ----------------
__global__ void wsum_fused(const ushort* __restrict__ Ah, const float* __restrict__ prt,
                           float* __restrict__ out) {
  int b = blockIdx.x, dc = blockIdx.y;   // grid (64,3), 128 threads
  int t = threadIdx.x;
  __shared__ float w[512];
  __shared__ float redm[2], reds[2];

  float s[4];
  #pragma unroll
  for (int i = 0; i < 4; ++i) {
    int r = b * 512 + t + i * 128;
    s[i] = prt[r] + prt[32768 + r] + prt[2 * 32768 + r] +
           prt[3 * 32768 + r] + prt[4 * 32768 + r] + prt[5 * 32768 + r];
  }
  float mx = fmaxf(fmaxf(s[0], s[1]), fmaxf(s[2], s[3]));
  #pragma unroll
  for (int o = 32; o >= 1; o >>= 1) mx = fmaxf(mx, __shfl_xor(mx, o));
  if ((t & 63) == 0) redm[t >> 6] = mx;
  __syncthreads();
  mx = fmaxf(redm[0], redm[1]);

  float e[4], sm = 0.f;
  #pragma unroll
  for (int i = 0; i < 4; ++i) { e[i] = __expf(s[i] - mx); sm += e[i]; }
  #pragma unroll
  for (int o = 32; o >= 1; o >>= 1) sm += __shfl_xor(sm, o);
  if ((t & 63) == 0) reds[t >> 6] = sm;
  __syncthreads();
  float inv = 1.0f / (reds[0] + reds[1]);
  #pragma unroll
  for (int i = 0; i < 4; ++i) w[t + i * 128] = e[i] * inv;
  __syncthreads();

  int d0 = dc * 256 + t * 2;
  const ushort* hp = Ah + (size_t)b * 512 * 768 + d0;
  float a0 = 0.f, a1 = 0.f;
  #pragma unroll 8
  for (int l = 0; l < 512; ++l) {
    unsigned u = *(const unsigned*)(hp + (size_t)l * 768);
    float wl = w[l];
    a0 += wl * (float)__builtin_bit_cast(_Float16, (unsigned short)(u & 0xffff));
    a1 += wl * (float)__builtin_bit_cast(_Float16, (unsigned short)(u >> 16));
  }
  out[b * 768 + d0] = a0;
  out[b * 768 + d0 + 1] = a1;

  if (dc == 0) {
    #pragma unroll
    for (int i = 0; i < 4; ++i)
      out[49152 + b * 512 + t + i * 128] = w[t + i * 128];
  }
}

// ---------------- launch ----------------
extern "C" void kernel_launch(void* const* d_in, const int* in_sizes, int n_in,
                              void* d_out, int out_size, void* d_ws, size_t ws_size,
                              hipStream_t stream) {
  const float* H    = (const float*)d_in[0];
  const float* W    = (const float*)d_in[1];
  const float* bias = (const float*)d_in[2];
  const float* cvec = (const float*)d_in[3];
  float* out = (float*)d_out;

  char* ws = (char*)d_ws;
  ushort* Ah = (ushort*)(ws + 0);              // 50,331,648 B
  ushort* Wt = (ushort*)(ws + 50331648);       //  1,179,648 B
  float*  prt = (float*)(ws + 51511296);       //    786,432 B ([6][32768])

  hipLaunchKernelGGL(convert_h, dim3(24576), dim3(256), 0, stream,
                     (const float4*)H, (ushort4*)Ah);
  hipLaunchKernelGGL(convert_w, dim3(576), dim3(256), 0, stream,
                     (const float4*)W, (ushort4*)Wt);
  hipLaunchKernelGGL(gemm_scores, dim3(1536), dim3(256), 0, stream,
                     Ah, Wt, bias, cvec, prt);
  hipLaunchKernelGGL(wsum_fused, dim3(64, 3), dim3(128), 0, stream,
                     Ah, prt, out);
}